// Round 13
// baseline (159.603 us; speedup 1.0000x reference)
//
#include <hip/hip_runtime.h>
#include <stdint.h>

// Problem constants (fixed by the reference)
#define NB       32
#define NC       128
#define NHW      1024            // H*W
#define NT       32768           // tokens
#define NE       16
#define NHID     512
#define NGBLK    512             // gate blocks (64 tokens each)

typedef __attribute__((ext_vector_type(8))) short short8v;   // 8 x bf16 (4 VGPRs)
typedef __attribute__((ext_vector_type(4))) float f32x4;
typedef __attribute__((ext_vector_type(2))) uint32_t uint2v;

__device__ __forceinline__ unsigned short f2bf(float f) {
    uint32_t u = __float_as_uint(f);
    uint32_t r = u + 0x7fffu + ((u >> 16) & 1u);   // RNE (finite values)
    return (unsigned short)(r >> 16);
}
__device__ __forceinline__ float bf2f(unsigned short u) {
    return __uint_as_float(((uint32_t)u) << 16);
}

#define WAIT_LGKM()      asm volatile("s_waitcnt lgkmcnt(0)" ::: "memory")
#define SBAR()           { asm volatile("" ::: "memory"); __builtin_amdgcn_s_barrier(); asm volatile("" ::: "memory"); }

// ---------------- Threefry-2x32, 20 rounds (JAX) ----------------
__device__ __forceinline__ uint32_t rotl32(uint32_t x, uint32_t d) {
    return (x << d) | (x >> (32u - d));
}

__device__ __forceinline__ void threefry2x32_20(uint32_t k0, uint32_t k1,
                                                uint32_t& x0, uint32_t& x1) {
    const uint32_t ks0 = k0, ks1 = k1, ks2 = k0 ^ k1 ^ 0x1BD11BDAu;
    x0 += ks0; x1 += ks1;
#define TFR(r) { x0 += x1; x1 = rotl32(x1, r); x1 ^= x0; }
    TFR(13u) TFR(15u) TFR(26u) TFR(6u)
    x0 += ks1; x1 += ks2 + 1u;
    TFR(17u) TFR(29u) TFR(16u) TFR(24u)
    x0 += ks2; x1 += ks0 + 2u;
    TFR(13u) TFR(15u) TFR(26u) TFR(6u)
    x0 += ks0; x1 += ks1 + 3u;
    TFR(17u) TFR(29u) TFR(16u) TFR(24u)
    x0 += ks1; x1 += ks2 + 4u;
    TFR(13u) TFR(15u) TFR(26u) TFR(6u)
    x0 += ks2; x1 += ks0 + 5u;
#undef TFR
}

__device__ __forceinline__ float erfinv_xla_f32(float x) {
    float w = -log1pf(-x * x);
    float p;
    if (w < 5.0f) {
        w = w - 2.5f;
        p = 2.81022636e-08f;
        p = fmaf(p, w, 3.43273939e-07f);
        p = fmaf(p, w, -3.5233877e-06f);
        p = fmaf(p, w, -4.39150654e-06f);
        p = fmaf(p, w, 0.00021858087f);
        p = fmaf(p, w, -0.00125372503f);
        p = fmaf(p, w, -0.00417768164f);
        p = fmaf(p, w, 0.246640727f);
        p = fmaf(p, w, 1.50140941f);
    } else {
        w = sqrtf(w) - 3.0f;
        p = -0.000200214257f;
        p = fmaf(p, w, 0.000100950558f);
        p = fmaf(p, w, 0.00134934322f);
        p = fmaf(p, w, -0.00367342844f);
        p = fmaf(p, w, 0.00573950773f);
        p = fmaf(p, w, -0.0076224613f);
        p = fmaf(p, w, 0.00943887047f);
        p = fmaf(p, w, 1.00167406f);
        p = fmaf(p, w, 2.83297682f);
    }
    return p * x;
}

__device__ __forceinline__ float jax_noise_elem(uint32_t i) {
    uint32_t x0 = 0u, x1 = i;
    threefry2x32_20(0u, 42u, x0, x1);
    uint32_t bits = x0 ^ x1;
    float f = __uint_as_float(0x3f800000u | (bits >> 9)) - 1.0f;
    const float lo = -0.99999994f;
    float u = f * 2.0f + lo;
    u = fmaxf(lo, u);
    return 1.41421354f * erfinv_xla_f32(u);
}

// ---------------- Fused kernel A: gate (blk<512) OR weight transpose ----------
__global__ __launch_bounds__(256) void moe_gate_tw_kernel(
    const float* __restrict__ x,
    const float* __restrict__ gate_w, const float* __restrict__ gate_b,
    const float* __restrict__ noise_w, const float* __restrict__ noise_b,
    float* __restrict__ gates_out,        // [T,16] region of d_out
    int*   __restrict__ top_idx,          // [T,2]
    float* __restrict__ top_prob,         // [T,2]
    int*   __restrict__ rank,             // [T,2] local ranks
    int*   __restrict__ bcnt,             // [512][16]
    unsigned short* __restrict__ xtb,     // [T,128] bf16
    const float* __restrict__ w1, unsigned short* __restrict__ w1bt,
    const float* __restrict__ w2, unsigned short* __restrict__ w2bt,
    int do_new)
{
    __shared__ union { float lw[32 * 160]; float ts[64][65]; } sm;
    __shared__ int lcnt[16];

    const int tid = threadIdx.x;

    if (blockIdx.x >= NGBLK) {
        // ---------------- transpose role ----------------
        int blk = blockIdx.x - NGBLK;
        const float* src;  unsigned short* dst;  int R, C;
        if (blk < 256) { src = w1; dst = w1bt; R = 128; C = 512; }
        else           { src = w2; dst = w2bt; R = 512; C = 128; blk -= 256; }
        const int nr = R >> 6, ncc = C >> 6;
        const int e = blk / (nr * ncc);
        const int rem = blk % (nr * ncc);
        const int rt = rem / ncc, ct = rem % ncc;
        const float* S = src + (size_t)e * R * C + (size_t)(rt * 64) * C + ct * 64;
        unsigned short* D = dst + (size_t)e * R * C + (size_t)(ct * 64) * R + rt * 64;
        #pragma unroll
        for (int i = 0; i < 16; ++i) {
            int lin = i * 256 + tid;
            int r = lin >> 6, c = lin & 63;
            sm.ts[r][c] = S[(size_t)r * C + c];
        }
        __syncthreads();
        #pragma unroll
        for (int i = 0; i < 16; ++i) {
            int lin = i * 256 + tid;
            int c = lin >> 6, r = lin & 63;
            D[(size_t)c * R + r] = f2bf(sm.ts[r][c]);
        }
        return;
    }

    // ---------------- gate role ----------------
    const int tl  = tid >> 2;                     // token within block (0..63)
    const int q   = tid & 3;                      // channel quarter
    const int t   = blockIdx.x * 64 + tl;         // global token
    const int b   = t >> 10, hw = t & 1023;

    if (tid < 16) lcnt[tid] = 0;

    for (int idx = tid; idx < 4096; idx += 256) {
        int ci = idx >> 7;
        int r  = idx & 127;
        int qq = r >> 5, e = r & 31;
        int c  = qq * 32 + ci;
        float v = (e < 16) ? gate_w[c * 16 + e] : noise_w[c * 16 + (e - 16)];
        sm.lw[ci * 160 + qq * 40 + e] = v;
    }
    __syncthreads();

    float acc[32];
    #pragma unroll
    for (int e = 0; e < 32; ++e) acc[e] = 0.f;

    unsigned short xh[32];
    const float* xq = x + (size_t)b * (NC * NHW) + (size_t)(q * 32) * NHW + hw;
    const float* wq = sm.lw + q * 40;
    #pragma unroll 4
    for (int ci = 0; ci < 32; ++ci) {
        float xv = xq[(size_t)ci << 10];
        xh[ci] = f2bf(xv);
        const f32x4* wr = (const f32x4*)(wq + ci * 160);
        #pragma unroll
        for (int j = 0; j < 8; ++j) {
            f32x4 w4 = wr[j];
            #pragma unroll
            for (int k = 0; k < 4; ++k)
                acc[j * 4 + k] = fmaf(xv, w4[k], acc[j * 4 + k]);
        }
    }

    if (do_new) {
        #pragma unroll
        for (int j = 0; j < 4; ++j) {
            short8v v;
            #pragma unroll
            for (int k = 0; k < 8; ++k) v[k] = (short)xh[j * 8 + k];
            *(short8v*)(xtb + (size_t)t * 128 + q * 32 + j * 8) = v;
        }
    }

    #pragma unroll
    for (int e = 0; e < 32; ++e) {
        acc[e] += __shfl_xor(acc[e], 1);
        acc[e] += __shfl_xor(acc[e], 2);
    }

    float lg[4];
    #pragma unroll
    for (int j = 0; j < 4; ++j) {
        int e = q * 4 + j;
        float g  = acc[e] + gate_b[e];
        float an = acc[16 + e] + noise_b[e];
        float sd = fmaxf(an, 0.f) + log1pf(expf(-fabsf(an)));
        float nz = jax_noise_elem((uint32_t)t * 16u + (uint32_t)e);
        lg[j] = fmaf(nz, sd, g);
    }

    // local top-2 (value desc, index asc — matches lax.top_k stability)
    float v1 = lg[0], v2 = -INFINITY;
    int   i1 = q * 4, i2 = 0x7fffffff;
    #pragma unroll
    for (int j = 1; j < 4; ++j) {
        float v = lg[j]; int e = q * 4 + j;
        if (v > v1) { v2 = v1; i2 = i1; v1 = v; i1 = e; }
        else if (v > v2) { v2 = v; i2 = e; }
    }
    #pragma unroll
    for (int m = 1; m <= 2; m <<= 1) {
        float pv1 = __shfl_xor(v1, m), pv2 = __shfl_xor(v2, m);
        int   pi1 = __shfl_xor(i1, m), pi2 = __shfl_xor(i2, m);
        bool pBest = (pv1 > v1) || (pv1 == v1 && pi1 < i1);
        float c2v; int c2i;
        if (pBest) { c2v = v1;  c2i = i1;  v1 = pv1; i1 = pi1;
                     if (!((c2v > pv2) || (c2v == pv2 && c2i < pi2))) { c2v = pv2; c2i = pi2; }
        } else     { c2v = pv1; c2i = pi1;
                     if (!((c2v > v2)  || (c2v == v2  && c2i < i2)))  { c2v = v2;  c2i = i2;  }
        }
        v2 = c2v; i2 = c2i;
    }

    float qq = expf(v2 - v1);
    float s  = 1.0f + qq;
    float p1 = 1.0f / s;
    float p2 = qq / s;

    f32x4 g4;
    #pragma unroll
    for (int j = 0; j < 4; ++j) {
        int e = q * 4 + j;
        g4[j] = (e == i1) ? p1 : ((e == i2) ? p2 : 0.f);
    }
    *(f32x4*)(gates_out + (size_t)t * 16 + q * 4) = g4;

    if (q == 0) {
        top_idx[t * 2 + 0] = i1;  top_idx[t * 2 + 1] = i2;
        top_prob[t * 2 + 0] = p1; top_prob[t * 2 + 1] = p2;
        if (do_new) {
            int r1 = atomicAdd(&lcnt[i1], 1);   // LDS atomics only
            int r2 = atomicAdd(&lcnt[i2], 1);
            rank[t * 2 + 0] = r1;
            rank[t * 2 + 1] = r2;
        }
    }
    if (do_new) {
        __syncthreads();                         // lcnt final
        if (tid < 16) bcnt[blockIdx.x * 16 + tid] = lcnt[tid];
    }
}

// ---- scan: hierarchical prefix over bcnt[512][16] -> poff, bbase, tables -----
__global__ __launch_bounds__(256) void scan_kernel(
    const int* __restrict__ bcnt,        // [512][16]
    int* __restrict__ poff, int* __restrict__ blk2e,
    int* __restrict__ blk2chunk, int* __restrict__ total_chunks,
    int* __restrict__ bbase,             // [512][16]
    int* __restrict__ pair_tok)
{
    __shared__ int ps[16][17];
    __shared__ int gb[16][17];
    __shared__ int scnt[16];
    __shared__ int snch[16];
    __shared__ int scum[17];
    __shared__ int spoff[16];
    const int tid = threadIdx.x;         // 256
    const int e = tid >> 4, g = tid & 15;

    int s = 0;
    for (int b = g * 32; b < g * 32 + 32; ++b)
        s += bcnt[b * 16 + e];
    ps[e][g] = s;
    __syncthreads();

    if (tid < 16) {
        int run = 0;
        for (int gg = 0; gg < 16; ++gg) { gb[tid][gg] = run; run += ps[tid][gg]; }
        scnt[tid] = run;
        snch[tid] = (run + 127) >> 7;
    }
    __syncthreads();

    if (tid == 0) {
        int cc = 0, off = 0;
        for (int ee = 0; ee < 16; ++ee) {
            scum[ee] = cc; spoff[ee] = off;
            cc += snch[ee]; off += snch[ee] << 7;
        }
        scum[16] = cc;
        *total_chunks = cc;
    }
    __syncthreads();
    const int tot = scum[16];
    for (int idx = tid; idx < tot; idx += 256) {
        int ee = 0;
        #pragma unroll
        for (int k = 0; k < 15; ++k)
            if (idx >= scum[k + 1]) ee = k + 1;
        blk2e[idx] = ee;
        blk2chunk[idx] = idx - scum[ee];
    }
    if (tid < 16) poff[tid] = spoff[tid];

    {
        int run = spoff[e] + gb[e][g];
        for (int b = g * 32; b < g * 32 + 32; ++b) {
            bbase[b * 16 + e] = run;
            run += bcnt[b * 16 + e];
        }
    }

    for (int ee = 0; ee < 16; ++ee) {
        int start = spoff[ee] + scnt[ee];
        int end   = spoff[ee] + (snch[ee] << 7);
        for (int i = start + tid; i < end; i += 256)
            pair_tok[i] = -1;
    }
}

// ---------------- scatter pairs into expert bins ------------------------------
__global__ __launch_bounds__(256) void scatter_kernel(
    const int* __restrict__ top_idx, const int* __restrict__ rank,
    const int* __restrict__ bbase, int* __restrict__ pair_tok,
    int* __restrict__ slot_of)
{
    int i = blockIdx.x * 256 + threadIdx.x;   // 0..65535
    int t = i >> 1;
    int e = top_idx[i];
    int slot = bbase[(t >> 6) * 16 + e] + rank[i];
    pair_tok[slot] = t;
    slot_of[i] = slot;
}

// ---------------- grouped MFMA MLP: 1 block = (expert, 128 pairs) -------------
// 8 waves (512 thr). NO weight staging: W1/W2 fragments read DIRECTLY from
// global (L2-resident via XCD swizzle — each XCD serves ~2 experts = 1 MB,
// m169 "don't stage L2-fit data"). X in registers (B-operand of swapped L1).
// LDS = Hs double-buffer ONLY (32 KB) -> 1 lgkm-drained barrier per chunk.
__global__ __launch_bounds__(512, 3) void moe_mfma_kernel(
    const unsigned short* __restrict__ xtb,
    const int* __restrict__ pair_tok, const int* __restrict__ blk2e,
    const int* __restrict__ blk2chunk, const int* __restrict__ poff,
    const int* __restrict__ total_chunks,
    const unsigned short* __restrict__ w1bt,   // [E][HID][D] bf16
    const float* __restrict__ b1,
    const unsigned short* __restrict__ w2bt,   // [E][D][HID] bf16
    const float* __restrict__ b2,
    unsigned short* __restrict__ pair_y)       // [Ppad][128] bf16
{
    __shared__ short Hs[2][128 * 64];  // [tok][hid] swz mask 7, double-buffered

    // XCD-aware swizzle: 528 = 8*66 (T1) -> expert locality per XCD L2.
    const int blk = (blockIdx.x & 7) * 66 + (blockIdx.x >> 3);
    if (blk >= *total_chunks) return;
    const int e  = blk2e[blk];
    const int p0 = poff[e] + (blk2chunk[blk] << 7);
    const int tid  = threadIdx.x;
    const int lane = tid & 63;
    const int wid  = tid >> 6;       // 0..7
    const int wm   = wid >> 2;       // 0..1: L1 hid-half / L2 d-half
    const int wn   = wid & 3;        // 0..3: token quarter (32 tokens)
    const int l16  = lane & 15;
    const int lg   = lane >> 4;      // 0..3

    const unsigned short* w1e = w1bt + (size_t)e * 512 * 128;
    const unsigned short* w2e = w2bt + (size_t)e * 128 * 512;

    // X tile in registers: this wave's 32 token rows x K=128 (8 b128 loads).
    short8v xa[2][4];
    #pragma unroll
    for (int ni = 0; ni < 2; ++ni) {
        int row = wn * 32 + ni * 16 + l16;
        int tok = pair_tok[p0 + row];
        #pragma unroll
        for (int kk = 0; kk < 4; ++kk) {
            short8v v = {};
            if (tok >= 0)
                v = *(const short8v*)(xtb + (size_t)tok * 128 + kk * 32 + lg * 8);
            xa[ni][kk] = v;
        }
    }

    f32x4 yacc[2][4];
    #pragma unroll
    for (int af = 0; af < 2; ++af)
        #pragma unroll
        for (int nj = 0; nj < 4; ++nj)
            yacc[af][nj] = (f32x4){0.f, 0.f, 0.f, 0.f};

    const int rowA0 = wn * 32 + l16, rowA1 = rowA0 + 16;

    for (int c = 0; c < 8; ++c) {
        short* Hb = (short*)Hs[c & 1];

        // ---- layer 1 (swapped): D[hid][tok] = W1_chunk(A, global) x X(B) ----
        f32x4 hacc[2][2];
        #pragma unroll
        for (int mi = 0; mi < 2; ++mi)
            #pragma unroll
            for (int ni = 0; ni < 2; ++ni)
                hacc[mi][ni] = (f32x4){0.f, 0.f, 0.f, 0.f};

        __builtin_amdgcn_s_setprio(1);
        #pragma unroll
        for (int kk = 0; kk < 4; ++kk) {
            int slot = kk * 4 + lg;
            #pragma unroll
            for (int mi = 0; mi < 2; ++mi) {
                int hr = (c << 6) + wm * 32 + mi * 16 + l16;   // global hid row
                short8v wfr = *(const short8v*)(w1e + (size_t)hr * 128 + slot * 8);
                #pragma unroll
                for (int ni = 0; ni < 2; ++ni)
                    hacc[mi][ni] = __builtin_amdgcn_mfma_f32_16x16x32_bf16(
                        wfr, xa[ni][kk], hacc[mi][ni], 0, 0, 0);
            }
        }
        __builtin_amdgcn_s_setprio(0);

        // relu + b1 -> Hs[c&1]. Lane holds 4 consecutive hid per token ->
        // packed b64 writes (swz mask 7).
        #pragma unroll
        for (int mi = 0; mi < 2; ++mi) {
            int h0 = wm * 32 + mi * 16 + lg * 4;               // local hid, %4==0
            f32x4 b1v = *(const f32x4*)(b1 + e * 512 + (c << 6) + h0);
            #pragma unroll
            for (int ni = 0; ni < 2; ++ni) {
                int tok = wn * 32 + ni * 16 + l16;
                float v0 = fmaxf(hacc[mi][ni][0] + b1v[0], 0.f);
                float v1 = fmaxf(hacc[mi][ni][1] + b1v[1], 0.f);
                float v2 = fmaxf(hacc[mi][ni][2] + b1v[2], 0.f);
                float v3 = fmaxf(hacc[mi][ni][3] + b1v[3], 0.f);
                uint32_t lo = (uint32_t)f2bf(v0) | ((uint32_t)f2bf(v1) << 16);
                uint32_t hi = (uint32_t)f2bf(v2) | ((uint32_t)f2bf(v3) << 16);
                int slot = h0 >> 3;
                int addr = tok * 64 + (((slot ^ (tok & 7))) << 3) + (h0 & 7);
                *(uint2v*)(Hb + addr) = (uint2v){lo, hi};
            }
        }
        // Single barrier per chunk. Drain covers: this chunk's Hs writes AND
        // the previous chunk's Hs ds_reads (R6 race class). Double-buffer
        // gives 2-chunk spacing for write-after-read on each Hs buffer.
        WAIT_LGKM(); SBAR();

        // ---- layer 2: Y += H_chunk(A, LDS) @ W2(B, global), tile 32x64 ----
        __builtin_amdgcn_s_setprio(1);
        #pragma unroll
        for (int kk = 0; kk < 2; ++kk) {
            int slot = kk * 4 + lg;
            short8v a0 = *(const short8v*)(Hb + rowA0 * 64 + ((slot ^ (rowA0 & 7)) * 8));
            short8v a1 = *(const short8v*)(Hb + rowA1 * 64 + ((slot ^ (rowA1 & 7)) * 8));
            #pragma unroll
            for (int nj = 0; nj < 4; ++nj) {
                int dr = wm * 64 + nj * 16 + l16;              // d row
                short8v bfr = *(const short8v*)(w2e + (size_t)dr * 512 + (c << 6) + slot * 8);
                yacc[0][nj] = __builtin_amdgcn_mfma_f32_16x16x32_bf16(a0, bfr, yacc[0][nj], 0, 0, 0);
                yacc[1][nj] = __builtin_amdgcn_mfma_f32_16x16x32_bf16(a1, bfr, yacc[1][nj], 0, 0, 0);
            }
        }
        __builtin_amdgcn_s_setprio(0);
        // no second barrier: next chunk's WAIT_LGKM+SBAR retires these reads
        // before Hs[c&1] is rewritten at chunk c+2 (dbuf spacing).
    }

    // epilogue: pair_y = bf16(Y + b2). Y D-frag: col=d (l16), rows=tok.
    #pragma unroll
    for (int nj = 0; nj < 4; ++nj) {
        int d = wm * 64 + nj * 16 + l16;
        float b2v = b2[e * 128 + d];
        #pragma unroll
        for (int af = 0; af < 2; ++af) {
            #pragma unroll
            for (int r = 0; r < 4; ++r) {
                int m = wn * 32 + af * 16 + lg * 4 + r;
                pair_y[(size_t)(p0 + m) * 128 + d] = f2bf(yacc[af][nj][r] + b2v);
            }
        }
    }
}

// ---------------- combine: out[t] = p0*y0 + p1*y1 (NCHW store) ----------------
__global__ __launch_bounds__(256) void combine_kernel(
    const unsigned short* __restrict__ pair_y, const int* __restrict__ slot_of,
    const float* __restrict__ top_prob, float* __restrict__ out)
{
    __shared__ float ob[64][129];
    const int blk = blockIdx.x;               // 512
    const int b = blk >> 4;
    const int hw0 = (blk & 15) << 6;
    const int tid = threadIdx.x;
    #pragma unroll
    for (int i = 0; i < 4; ++i) {
        int lin = i * 256 + tid;              // 0..1023
        int tl = lin >> 4, dg = lin & 15;
        int t = b * 1024 + hw0 + tl;
        int s0 = slot_of[t * 2], s1 = slot_of[t * 2 + 1];
        float p0 = top_prob[t * 2], p1 = top_prob[t * 2 + 1];
        short8v y0 = *(const short8v*)(pair_y + (size_t)s0 * 128 + dg * 8);
        short8v y1 = *(const short8v*)(pair_y + (size_t)s1 * 128 + dg * 8);
        #pragma unroll
        for (int j = 0; j < 8; ++j)
            ob[tl][dg * 8 + j] = p0 * bf2f((unsigned short)y0[j]) + p1 * bf2f((unsigned short)y1[j]);
    }
    __syncthreads();
    #pragma unroll
    for (int i = 0; i < 32; ++i) {
        int lin = i * 256 + tid;
        int d = lin >> 6, hwl = lin & 63;
        out[((size_t)b * 128 + d) * 1024 + hw0 + hwl] = ob[hwl][d];
    }
}

// ---------------- fallback per-token expert kernel ----------------------------
__global__ __launch_bounds__(256) void moe_expert_kernel(
    const float* __restrict__ x,
    const int* __restrict__ top_idx, const float* __restrict__ top_prob,
    const float* __restrict__ w1, const float* __restrict__ b1,
    const float* __restrict__ w2, const float* __restrict__ b2,
    float* __restrict__ out)
{
    __shared__ float xsB[128];
    __shared__ float hb[512];

    const int tid = threadIdx.x;
    const int t = blockIdx.x;
    const int b = t >> 10, hw = t & 1023;

    if (tid < 128)
        xsB[tid] = x[((size_t)b * 128 + tid) * NHW + hw];
    __syncthreads();

    float oacc = 0.f;
    #pragma unroll
    for (int k = 0; k < 2; ++k) {
        const int e = top_idx[t * 2 + k];
        const float pw = top_prob[t * 2 + k];
        const float* W1 = w1 + (size_t)e * (128 * 512);
        float a0 = 0.f, a1 = 0.f;
        for (int d = 0; d < 128; ++d) {
            float xv = xsB[d];
            a0 = fmaf(xv, W1[d * 512 + tid], a0);
            a1 = fmaf(xv, W1[d * 512 + tid + 256], a1);
        }
        hb[tid]       = fmaxf(a0 + b1[e * 512 + tid], 0.f);
        hb[tid + 256] = fmaxf(a1 + b1[e * 512 + tid + 256], 0.f);
        __syncthreads();
        if (tid < 128) {
            const float* W2 = w2 + (size_t)e * (512 * 128);
            float a = 0.f;
            for (int h = 0; h < 512; ++h)
                a = fmaf(hb[h], W2[h * 128 + tid], a);
            oacc = fmaf(pw, a + b2[e * 128 + tid], oacc);
        }
        __syncthreads();
    }
    if (tid < 128)
        out[((size_t)b * 128 + tid) * NHW + hw] = oacc;
}

// ---------------- host launch -------------------------------------------------
extern "C" void kernel_launch(void* const* d_in, const int* in_sizes, int n_in,
                              void* d_out, int out_size, void* d_ws, size_t ws_size,
                              hipStream_t stream) {
    const float* x       = (const float*)d_in[0];
    const float* gate_w  = (const float*)d_in[1];
    const float* gate_b  = (const float*)d_in[2];
    const float* noise_w = (const float*)d_in[3];
    const float* noise_b = (const float*)d_in[4];
    const float* w1      = (const float*)d_in[5];
    const float* b1      = (const float*)d_in[6];
    const float* w2      = (const float*)d_in[7];
    const float* b2      = (const float*)d_in[8];

    float* out   = (float*)d_out;                   // [32,128,32,32]
    float* gates = out + (size_t)NB * NC * NHW;     // [T,16]

    // workspace layout (byte offsets)
    const size_t OFF_POFF   = 0;          // 16 ints
    const size_t OFF_TOTAL  = 1024;       // 1 int
    const size_t OFF_B2E    = 4096;       // 544 ints
    const size_t OFF_B2C    = 8192;       // 544 ints
    const size_t OFF_TIDX   = 12288;      // T*2 ints
    const size_t OFF_RANK   = OFF_TIDX  + (size_t)NT * 2 * 4;
    const size_t OFF_SLOT   = OFF_RANK  + (size_t)NT * 2 * 4;
    const size_t OFF_PROB   = OFF_SLOT  + (size_t)NT * 2 * 4;
    const size_t OFF_BCNT   = OFF_PROB  + (size_t)NT * 2 * 4;     // 512*16 ints
    const size_t OFF_BBASE  = OFF_BCNT  + (size_t)NGBLK * 16 * 4;
    const size_t OFF_XTB    = OFF_BBASE + (size_t)NGBLK * 16 * 4;
    const size_t OFF_W1BT   = OFF_XTB   + (size_t)NT * 128 * 2;
    const size_t OFF_W2BT   = OFF_W1BT  + (size_t)NE * 512 * 128 * 2;
    const size_t OFF_PTOK   = OFF_W2BT  + (size_t)NE * 128 * 512 * 2;
    const size_t NPAIR_PAD  = 67584;
    const size_t OFF_PAIRY  = OFF_PTOK  + NPAIR_PAD * 4;
    const size_t NEED       = OFF_PAIRY + NPAIR_PAD * 128 * 2;   // pair_y bf16

    char* ws = (char*)d_ws;
    int*   poff     = (int*)(ws + OFF_POFF);
    int*   total_ch = (int*)(ws + OFF_TOTAL);
    int*   blk2e    = (int*)(ws + OFF_B2E);
    int*   blk2c    = (int*)(ws + OFF_B2C);
    int*   top_idx  = (int*)(ws + OFF_TIDX);
    int*   rank     = (int*)(ws + OFF_RANK);
    int*   slot_of  = (int*)(ws + OFF_SLOT);
    float* top_prob = (float*)(ws + OFF_PROB);
    int*   bcnt     = (int*)(ws + OFF_BCNT);
    int*   bbase    = (int*)(ws + OFF_BBASE);
    unsigned short* xtb    = (unsigned short*)(ws + OFF_XTB);
    unsigned short* w1bt   = (unsigned short*)(ws + OFF_W1BT);
    unsigned short* w2bt   = (unsigned short*)(ws + OFF_W2BT);
    int*   pair_tok = (int*)(ws + OFF_PTOK);
    unsigned short* pair_y = (unsigned short*)(ws + OFF_PAIRY);

    const int use_new = (ws_size >= NEED) ? 1 : 0;

    // gate (blocks 0..511) + weight transpose (blocks 512..1023) in one launch
    moe_gate_tw_kernel<<<use_new ? (NGBLK + 512) : NGBLK, 256, 0, stream>>>(
        x, gate_w, gate_b, noise_w, noise_b,
        gates, top_idx, top_prob, rank, bcnt, xtb,
        w1, w1bt, w2, w2bt, use_new);

    if (use_new) {
        scan_kernel<<<1, 256, 0, stream>>>(bcnt, poff, blk2e, blk2c, total_ch,
                                           bbase, pair_tok);
        scatter_kernel<<<NT * 2 / 256, 256, 0, stream>>>(top_idx, rank, bbase,
                                                         pair_tok, slot_of);
        moe_mfma_kernel<<<528, 512, 0, stream>>>(
            xtb, pair_tok, blk2e, blk2c, poff, total_ch,
            w1bt, b1, w2bt, b2, pair_y);
        combine_kernel<<<512, 256, 0, stream>>>(pair_y, slot_of, top_prob, out);
    } else {
        moe_expert_kernel<<<NT, 256, 0, stream>>>(
            x, top_idx, top_prob, w1, b1, w2, b2, out);
    }
}

// Round 14
// 87.216 us; speedup vs baseline: 1.8300x; 1.8300x over previous
//
#include <hip/hip_runtime.h>
#include <stdint.h>

// Problem constants (fixed by the reference)
#define NB       32
#define NC       128
#define NHW      1024            // H*W
#define NT       32768           // tokens
#define NE       16
#define NHID     512
#define NGBLK    512             // gate blocks (64 tokens each)

typedef __attribute__((ext_vector_type(8))) short short8v;   // 8 x bf16 (4 VGPRs)
typedef __attribute__((ext_vector_type(4))) float f32x4;
typedef __attribute__((ext_vector_type(2))) uint32_t uint2v;

__device__ __forceinline__ unsigned short f2bf(float f) {
    uint32_t u = __float_as_uint(f);
    uint32_t r = u + 0x7fffu + ((u >> 16) & 1u);   // RNE (finite values)
    return (unsigned short)(r >> 16);
}
__device__ __forceinline__ float bf2f(unsigned short u) {
    return __uint_as_float(((uint32_t)u) << 16);
}

// async global->LDS, 16B per lane; LDS dest = wave-uniform base + lane*16,
// so swizzling is done on the per-lane GLOBAL source address (m173 pattern).
__device__ __forceinline__ void gll16(const void* g, void* l) {
    __builtin_amdgcn_global_load_lds(
        (const __attribute__((address_space(1))) uint32_t*)g,
        (__attribute__((address_space(3))) uint32_t*)l, 16, 0, 0);
}

#define WAIT_VM2_LGKM0() asm volatile("s_waitcnt vmcnt(2) lgkmcnt(0)" ::: "memory")
#define WAIT_VM0_LGKM0() asm volatile("s_waitcnt vmcnt(0) lgkmcnt(0)" ::: "memory")
#define WAIT_LGKM()      asm volatile("s_waitcnt lgkmcnt(0)" ::: "memory")
#define SBAR()           { asm volatile("" ::: "memory"); __builtin_amdgcn_s_barrier(); asm volatile("" ::: "memory"); }

// ---------------- Threefry-2x32, 20 rounds (JAX) ----------------
__device__ __forceinline__ uint32_t rotl32(uint32_t x, uint32_t d) {
    return (x << d) | (x >> (32u - d));
}

__device__ __forceinline__ void threefry2x32_20(uint32_t k0, uint32_t k1,
                                                uint32_t& x0, uint32_t& x1) {
    const uint32_t ks0 = k0, ks1 = k1, ks2 = k0 ^ k1 ^ 0x1BD11BDAu;
    x0 += ks0; x1 += ks1;
#define TFR(r) { x0 += x1; x1 = rotl32(x1, r); x1 ^= x0; }
    TFR(13u) TFR(15u) TFR(26u) TFR(6u)
    x0 += ks1; x1 += ks2 + 1u;
    TFR(17u) TFR(29u) TFR(16u) TFR(24u)
    x0 += ks2; x1 += ks0 + 2u;
    TFR(13u) TFR(15u) TFR(26u) TFR(6u)
    x0 += ks0; x1 += ks1 + 3u;
    TFR(17u) TFR(29u) TFR(16u) TFR(24u)
    x0 += ks1; x1 += ks2 + 4u;
    TFR(13u) TFR(15u) TFR(26u) TFR(6u)
    x0 += ks2; x1 += ks0 + 5u;
#undef TFR
}

__device__ __forceinline__ float erfinv_xla_f32(float x) {
    float w = -log1pf(-x * x);
    float p;
    if (w < 5.0f) {
        w = w - 2.5f;
        p = 2.81022636e-08f;
        p = fmaf(p, w, 3.43273939e-07f);
        p = fmaf(p, w, -3.5233877e-06f);
        p = fmaf(p, w, -4.39150654e-06f);
        p = fmaf(p, w, 0.00021858087f);
        p = fmaf(p, w, -0.00125372503f);
        p = fmaf(p, w, -0.00417768164f);
        p = fmaf(p, w, 0.246640727f);
        p = fmaf(p, w, 1.50140941f);
    } else {
        w = sqrtf(w) - 3.0f;
        p = -0.000200214257f;
        p = fmaf(p, w, 0.000100950558f);
        p = fmaf(p, w, 0.00134934322f);
        p = fmaf(p, w, -0.00367342844f);
        p = fmaf(p, w, 0.00573950773f);
        p = fmaf(p, w, -0.0076224613f);
        p = fmaf(p, w, 0.00943887047f);
        p = fmaf(p, w, 1.00167406f);
        p = fmaf(p, w, 2.83297682f);
    }
    return p * x;
}

__device__ __forceinline__ float jax_noise_elem(uint32_t i) {
    uint32_t x0 = 0u, x1 = i;
    threefry2x32_20(0u, 42u, x0, x1);
    uint32_t bits = x0 ^ x1;
    float f = __uint_as_float(0x3f800000u | (bits >> 9)) - 1.0f;
    const float lo = -0.99999994f;
    float u = f * 2.0f + lo;
    u = fmaxf(lo, u);
    return 1.41421354f * erfinv_xla_f32(u);
}

// ---------------- Fused kernel A: gate (blk<512) OR weight transpose ----------
__global__ __launch_bounds__(256) void moe_gate_tw_kernel(
    const float* __restrict__ x,
    const float* __restrict__ gate_w, const float* __restrict__ gate_b,
    const float* __restrict__ noise_w, const float* __restrict__ noise_b,
    float* __restrict__ gates_out,        // [T,16] region of d_out
    int*   __restrict__ top_idx,          // [T,2]
    float* __restrict__ top_prob,         // [T,2]
    int*   __restrict__ rank,             // [T,2] local ranks
    int*   __restrict__ bcnt,             // [512][16]
    unsigned short* __restrict__ xtb,     // [T,128] bf16
    const float* __restrict__ w1, unsigned short* __restrict__ w1bt,
    const float* __restrict__ w2, unsigned short* __restrict__ w2bt,
    int do_new)
{
    __shared__ union { float lw[32 * 160]; float ts[64][65]; } sm;
    __shared__ int lcnt[16];

    const int tid = threadIdx.x;

    if (blockIdx.x >= NGBLK) {
        // ---------------- transpose role ----------------
        int blk = blockIdx.x - NGBLK;
        const float* src;  unsigned short* dst;  int R, C;
        if (blk < 256) { src = w1; dst = w1bt; R = 128; C = 512; }
        else           { src = w2; dst = w2bt; R = 512; C = 128; blk -= 256; }
        const int nr = R >> 6, ncc = C >> 6;
        const int e = blk / (nr * ncc);
        const int rem = blk % (nr * ncc);
        const int rt = rem / ncc, ct = rem % ncc;
        const float* S = src + (size_t)e * R * C + (size_t)(rt * 64) * C + ct * 64;
        unsigned short* D = dst + (size_t)e * R * C + (size_t)(ct * 64) * R + rt * 64;
        #pragma unroll
        for (int i = 0; i < 16; ++i) {
            int lin = i * 256 + tid;
            int r = lin >> 6, c = lin & 63;
            sm.ts[r][c] = S[(size_t)r * C + c];
        }
        __syncthreads();
        #pragma unroll
        for (int i = 0; i < 16; ++i) {
            int lin = i * 256 + tid;
            int c = lin >> 6, r = lin & 63;
            D[(size_t)c * R + r] = f2bf(sm.ts[r][c]);
        }
        return;
    }

    // ---------------- gate role ----------------
    const int tl  = tid >> 2;                     // token within block (0..63)
    const int q   = tid & 3;                      // channel quarter
    const int t   = blockIdx.x * 64 + tl;         // global token
    const int b   = t >> 10, hw = t & 1023;

    if (tid < 16) lcnt[tid] = 0;

    for (int idx = tid; idx < 4096; idx += 256) {
        int ci = idx >> 7;
        int r  = idx & 127;
        int qq = r >> 5, e = r & 31;
        int c  = qq * 32 + ci;
        float v = (e < 16) ? gate_w[c * 16 + e] : noise_w[c * 16 + (e - 16)];
        sm.lw[ci * 160 + qq * 40 + e] = v;
    }
    __syncthreads();

    float acc[32];
    #pragma unroll
    for (int e = 0; e < 32; ++e) acc[e] = 0.f;

    unsigned short xh[32];
    const float* xq = x + (size_t)b * (NC * NHW) + (size_t)(q * 32) * NHW + hw;
    const float* wq = sm.lw + q * 40;
    #pragma unroll 4
    for (int ci = 0; ci < 32; ++ci) {
        float xv = xq[(size_t)ci << 10];
        xh[ci] = f2bf(xv);
        const f32x4* wr = (const f32x4*)(wq + ci * 160);
        #pragma unroll
        for (int j = 0; j < 8; ++j) {
            f32x4 w4 = wr[j];
            #pragma unroll
            for (int k = 0; k < 4; ++k)
                acc[j * 4 + k] = fmaf(xv, w4[k], acc[j * 4 + k]);
        }
    }

    if (do_new) {
        #pragma unroll
        for (int j = 0; j < 4; ++j) {
            short8v v;
            #pragma unroll
            for (int k = 0; k < 8; ++k) v[k] = (short)xh[j * 8 + k];
            *(short8v*)(xtb + (size_t)t * 128 + q * 32 + j * 8) = v;
        }
    }

    #pragma unroll
    for (int e = 0; e < 32; ++e) {
        acc[e] += __shfl_xor(acc[e], 1);
        acc[e] += __shfl_xor(acc[e], 2);
    }

    float lg[4];
    #pragma unroll
    for (int j = 0; j < 4; ++j) {
        int e = q * 4 + j;
        float g  = acc[e] + gate_b[e];
        float an = acc[16 + e] + noise_b[e];
        float sd = fmaxf(an, 0.f) + log1pf(expf(-fabsf(an)));
        float nz = jax_noise_elem((uint32_t)t * 16u + (uint32_t)e);
        lg[j] = fmaf(nz, sd, g);
    }

    // local top-2 (value desc, index asc — matches lax.top_k stability)
    float v1 = lg[0], v2 = -INFINITY;
    int   i1 = q * 4, i2 = 0x7fffffff;
    #pragma unroll
    for (int j = 1; j < 4; ++j) {
        float v = lg[j]; int e = q * 4 + j;
        if (v > v1) { v2 = v1; i2 = i1; v1 = v; i1 = e; }
        else if (v > v2) { v2 = v; i2 = e; }
    }
    #pragma unroll
    for (int m = 1; m <= 2; m <<= 1) {
        float pv1 = __shfl_xor(v1, m), pv2 = __shfl_xor(v2, m);
        int   pi1 = __shfl_xor(i1, m), pi2 = __shfl_xor(i2, m);
        bool pBest = (pv1 > v1) || (pv1 == v1 && pi1 < i1);
        float c2v; int c2i;
        if (pBest) { c2v = v1;  c2i = i1;  v1 = pv1; i1 = pi1;
                     if (!((c2v > pv2) || (c2v == pv2 && c2i < pi2))) { c2v = pv2; c2i = pi2; }
        } else     { c2v = pv1; c2i = pi1;
                     if (!((c2v > v2)  || (c2v == v2  && c2i < i2)))  { c2v = v2;  c2i = i2;  }
        }
        v2 = c2v; i2 = c2i;
    }

    float qq = expf(v2 - v1);
    float s  = 1.0f + qq;
    float p1 = 1.0f / s;
    float p2 = qq / s;

    f32x4 g4;
    #pragma unroll
    for (int j = 0; j < 4; ++j) {
        int e = q * 4 + j;
        g4[j] = (e == i1) ? p1 : ((e == i2) ? p2 : 0.f);
    }
    *(f32x4*)(gates_out + (size_t)t * 16 + q * 4) = g4;

    if (q == 0) {
        top_idx[t * 2 + 0] = i1;  top_idx[t * 2 + 1] = i2;
        top_prob[t * 2 + 0] = p1; top_prob[t * 2 + 1] = p2;
        if (do_new) {
            int r1 = atomicAdd(&lcnt[i1], 1);   // LDS atomics only
            int r2 = atomicAdd(&lcnt[i2], 1);
            rank[t * 2 + 0] = r1;
            rank[t * 2 + 1] = r2;
        }
    }
    if (do_new) {
        __syncthreads();                         // lcnt final
        if (tid < 16) bcnt[blockIdx.x * 16 + tid] = lcnt[tid];
    }
}

// ---- scatter2: scan recomputed per-block (redundant) + scatter + tables ------
// 256 blocks x 256 thr; block covers 128 tokens (gate-blocks 2*blk, 2*blk+1).
// Block 0 additionally publishes poff/blk2e/blk2chunk/total and pad-fills.
__global__ __launch_bounds__(256) void scatter2_kernel(
    const int* __restrict__ bcnt,        // [512][16]
    const int* __restrict__ top_idx, const int* __restrict__ rank,
    int* __restrict__ poff, int* __restrict__ blk2e,
    int* __restrict__ blk2chunk, int* __restrict__ total_chunks,
    int* __restrict__ pair_tok, int* __restrict__ slot_of)
{
    __shared__ int ps[16][17];     // stripe sums [e][s], s = 32 gate-blocks
    __shared__ int cum[16][17];    // exclusive prefix of stripes
    __shared__ int scnt[16];
    __shared__ int snch[16];
    __shared__ int scum[17];
    __shared__ int spoff[16];
    __shared__ int lbase[2][16];   // bases for this block's two gate-blocks

    const int tid = threadIdx.x;
    const int e = tid >> 4, s = tid & 15;

    int a = 0;
    for (int b = s * 32; b < s * 32 + 32; ++b)
        a += bcnt[b * 16 + e];
    ps[e][s] = a;
    __syncthreads();

    if (tid < 16) {                // tid == e
        int run = 0;
        for (int ss = 0; ss < 16; ++ss) { cum[tid][ss] = run; run += ps[tid][ss]; }
        scnt[tid] = run;
        snch[tid] = (run + 127) >> 7;
    }
    __syncthreads();

    if (tid == 0) {
        int cc = 0, off = 0;
        for (int ee = 0; ee < 16; ++ee) {
            scum[ee] = cc; spoff[ee] = off;
            cc += snch[ee]; off += snch[ee] << 7;
        }
        scum[16] = cc;
    }
    __syncthreads();

    // bases for this block's two gate-blocks
    if (tid < 32) {
        int ee = tid >> 1, w = tid & 1;
        int g = (int)blockIdx.x * 2 + w;
        int sg = g >> 5;
        int part = cum[ee][sg];
        for (int b = sg * 32; b < g; ++b) part += bcnt[b * 16 + ee];
        lbase[w][ee] = spoff[ee] + part;
    }

    if (blockIdx.x == 0) {
        if (tid < 16) poff[tid] = spoff[tid];
        if (tid == 0) *total_chunks = scum[16];
        const int tot = scum[16];
        for (int idx = tid; idx < tot; idx += 256) {
            int ee = 0;
            #pragma unroll
            for (int k = 0; k < 15; ++k)
                if (idx >= scum[k + 1]) ee = k + 1;
            blk2e[idx] = ee;
            blk2chunk[idx] = idx - scum[ee];
        }
        for (int ee = 0; ee < 16; ++ee) {
            int start = spoff[ee] + scnt[ee];
            int end   = spoff[ee] + (snch[ee] << 7);
            for (int i = start + tid; i < end; i += 256)
                pair_tok[i] = -1;                 // pads disjoint from real slots
        }
    }
    __syncthreads();                              // lbase ready

    int i = (int)blockIdx.x * 256 + tid;          // pair index 0..65535
    int t = i >> 1;
    int ee = top_idx[i];
    int g = (t >> 6) & 1;
    int slot = lbase[g][ee] + rank[i];
    pair_tok[slot] = t;
    slot_of[i] = slot;
}

// ---------------- grouped MFMA MLP: 1 block = (expert, 128 pairs) -------------
// 8 waves (512 thr). X in registers (B-operand). L1 computes D[hid][tok]
// (swapped operands) -> packed b64 Hs writes. LDS = 48KB -> 3 blocks/CU.
// Counted-vmcnt pipeline (R9 schedule + R12 layout): top vmcnt(2) keeps W2(c)
// flying under layer-1; mid vmcnt(0) drains it where it's first needed.
__device__ __forceinline__ void stage_w1(const unsigned short* w1e, short* W1s,
                                         int hcn, int wid, int lane) {
    #pragma unroll
    for (int k2 = 0; k2 < 2; ++k2) {
        int i2 = wid * 2 + k2;                  // 0..15 x 1KB
        int r2 = i2 * 4 + (lane >> 4);          // hid-local row 0..63
        int s2 = lane & 15;                      // 16B slot 0..15
        gll16(w1e + (size_t)(hcn + r2) * 128 + ((s2 ^ (r2 & 15)) * 8),
              W1s + i2 * 512);
    }
}
__device__ __forceinline__ void stage_w2(const unsigned short* w2e, short* W2s,
                                         int hcn, int wid, int lane) {
    #pragma unroll
    for (int k2 = 0; k2 < 2; ++k2) {
        int i2 = wid * 2 + k2;                  // 0..15 x 1KB
        int r2 = i2 * 8 + (lane >> 3);          // d row 0..127
        int s2 = lane & 7;                       // 16B slot 0..7
        gll16(w2e + (size_t)r2 * 512 + hcn + ((s2 ^ (r2 & 7)) * 8),
              W2s + i2 * 512);
    }
}

__global__ __launch_bounds__(512, 4) void moe_mfma_kernel(
    const unsigned short* __restrict__ xtb,
    const int* __restrict__ pair_tok, const int* __restrict__ blk2e,
    const int* __restrict__ blk2chunk, const int* __restrict__ poff,
    const int* __restrict__ total_chunks,
    const unsigned short* __restrict__ w1bt,   // [E][HID][D] bf16
    const float* __restrict__ b1,
    const unsigned short* __restrict__ w2bt,   // [E][D][HID] bf16
    const float* __restrict__ b2,
    unsigned short* __restrict__ pair_y)       // [Ppad][128] bf16
{
    __shared__ short Hs[128 * 64];     // [tok][hid] swz mask 7  (16 KB)
    __shared__ short W1s[64 * 128];    // [hid][d]   swz mask 15 (16 KB)
    __shared__ short W2s[128 * 64];    // [d][hid]   swz mask 7  (16 KB)

    // XCD-aware swizzle: 528 = 8*66 (T1).
    const int blk = (blockIdx.x & 7) * 66 + (blockIdx.x >> 3);
    if (blk >= *total_chunks) return;
    const int e  = blk2e[blk];
    const int p0 = poff[e] + (blk2chunk[blk] << 7);
    const int tid  = threadIdx.x;
    const int lane = tid & 63;
    const int wid  = tid >> 6;       // 0..7
    const int wm   = wid >> 2;       // 0..1: L1 hid-half / L2 d-half
    const int wn   = wid & 3;        // 0..3: token quarter (32 tokens)
    const int l16  = lane & 15;
    const int lg   = lane >> 4;      // 0..3

    const unsigned short* w1e = w1bt + (size_t)e * 512 * 128;
    const unsigned short* w2e = w2bt + (size_t)e * 128 * 512;

    // prologue: W1(0), W2(0) oldest in the vmcnt FIFO, then X reg loads.
    stage_w1(w1e, W1s, 0, wid, lane);
    stage_w2(w2e, W2s, 0, wid, lane);

    short8v xa[2][4];
    #pragma unroll
    for (int ni = 0; ni < 2; ++ni) {
        int row = wn * 32 + ni * 16 + l16;
        int tok = pair_tok[p0 + row];
        #pragma unroll
        for (int kk = 0; kk < 4; ++kk) {
            short8v v = {};
            if (tok >= 0)
                v = *(const short8v*)(xtb + (size_t)tok * 128 + kk * 32 + lg * 8);
            xa[ni][kk] = v;
        }
    }

    f32x4 yacc[2][4];
    #pragma unroll
    for (int af = 0; af < 2; ++af)
        #pragma unroll
        for (int nj = 0; nj < 4; ++nj)
            yacc[af][nj] = (f32x4){0.f, 0.f, 0.f, 0.f};

    const int rowA0 = wn * 32 + l16, rowA1 = rowA0 + 16;

    for (int c = 0; c < 8; ++c) {
        // Top: W1(c) landed (it's older than the 2 W2(c) ops); W2(c) may fly.
        // (At c=0 this also over-waits most X loads — prologue only.)
        WAIT_VM2_LGKM0(); SBAR();

        // ---- layer 1 (swapped): D[hid][tok] = W1_chunk(A) x X(B) ----
        f32x4 hacc[2][2];
        #pragma unroll
        for (int mi = 0; mi < 2; ++mi)
            #pragma unroll
            for (int ni = 0; ni < 2; ++ni)
                hacc[mi][ni] = (f32x4){0.f, 0.f, 0.f, 0.f};

        __builtin_amdgcn_s_setprio(1);
        #pragma unroll
        for (int kk = 0; kk < 4; ++kk) {
            int slot = kk * 4 + lg;
            #pragma unroll
            for (int mi = 0; mi < 2; ++mi) {
                int hr = wm * 32 + mi * 16 + l16;          // hid row (A)
                short8v wfr = *(const short8v*)(W1s + hr * 128 + ((slot ^ (hr & 15)) * 8));
                #pragma unroll
                for (int ni = 0; ni < 2; ++ni)
                    hacc[mi][ni] = __builtin_amdgcn_mfma_f32_16x16x32_bf16(
                        wfr, xa[ni][kk], hacc[mi][ni], 0, 0, 0);
            }
        }
        __builtin_amdgcn_s_setprio(0);

        // relu + b1 -> Hs: lane holds 4 consecutive hid per token -> b64 write.
        #pragma unroll
        for (int mi = 0; mi < 2; ++mi) {
            int h0 = wm * 32 + mi * 16 + lg * 4;           // local hid, %4==0
            f32x4 b1v = *(const f32x4*)(b1 + e * 512 + (c << 6) + h0);
            #pragma unroll
            for (int ni = 0; ni < 2; ++ni) {
                int tok = wn * 32 + ni * 16 + l16;
                float v0 = fmaxf(hacc[mi][ni][0] + b1v[0], 0.f);
                float v1 = fmaxf(hacc[mi][ni][1] + b1v[1], 0.f);
                float v2 = fmaxf(hacc[mi][ni][2] + b1v[2], 0.f);
                float v3 = fmaxf(hacc[mi][ni][3] + b1v[3], 0.f);
                uint32_t lo = (uint32_t)f2bf(v0) | ((uint32_t)f2bf(v1) << 16);
                uint32_t hi = (uint32_t)f2bf(v2) | ((uint32_t)f2bf(v3) << 16);
                int slot = h0 >> 3;
                int addr = tok * 64 + ((slot ^ (tok & 7)) << 3) + (h0 & 7);
                *(uint2v*)(Hs + addr) = (uint2v){lo, hi};
            }
        }
        // Mid: Hs writes visible; W1s reads retired (lgkm0); W2(c) landed
        // (vmcnt0) exactly where layer 2 first needs it.
        WAIT_VM0_LGKM0(); SBAR();

        if (c < 7) stage_w1(w1e, W1s, (c + 1) << 6, wid, lane);  // under L2

        // ---- layer 2: Y += H_chunk @ W2[hc:hc+64, :], wave tile 32x64 ----
        __builtin_amdgcn_s_setprio(1);
        #pragma unroll
        for (int kk = 0; kk < 2; ++kk) {
            int slot = kk * 4 + lg;
            short8v a0 = *(const short8v*)(Hs + rowA0 * 64 + ((slot ^ (rowA0 & 7)) * 8));
            short8v a1 = *(const short8v*)(Hs + rowA1 * 64 + ((slot ^ (rowA1 & 7)) * 8));
            #pragma unroll
            for (int nj = 0; nj < 4; ++nj) {
                int dr = wm * 64 + nj * 16 + l16;
                short8v bfr = *(const short8v*)(W2s + dr * 64 + ((slot ^ (dr & 7)) * 8));
                yacc[0][nj] = __builtin_amdgcn_mfma_f32_16x16x32_bf16(a0, bfr, yacc[0][nj], 0, 0, 0);
                yacc[1][nj] = __builtin_amdgcn_mfma_f32_16x16x32_bf16(a1, bfr, yacc[1][nj], 0, 0, 0);
            }
        }
        __builtin_amdgcn_s_setprio(0);
        // End: all L2 ds_reads retired before stage_w2 overwrites W2s (R6).
        WAIT_LGKM(); SBAR();

        if (c < 7) stage_w2(w2e, W2s, (c + 1) << 6, wid, lane);
    }

    // epilogue: pair_y = bf16(Y + b2). Y D-frag: col=d (l16), rows=tok.
    #pragma unroll
    for (int nj = 0; nj < 4; ++nj) {
        int d = wm * 64 + nj * 16 + l16;
        float b2v = b2[e * 128 + d];
        #pragma unroll
        for (int af = 0; af < 2; ++af) {
            #pragma unroll
            for (int r = 0; r < 4; ++r) {
                int m = wn * 32 + af * 16 + lg * 4 + r;
                pair_y[(size_t)(p0 + m) * 128 + d] = f2bf(yacc[af][nj][r] + b2v);
            }
        }
    }
}

// ---------------- combine: out[t] = p0*y0 + p1*y1 (NCHW store) ----------------
__global__ __launch_bounds__(256) void combine_kernel(
    const unsigned short* __restrict__ pair_y, const int* __restrict__ slot_of,
    const float* __restrict__ top_prob, float* __restrict__ out)
{
    __shared__ float ob[64][129];
    const int blk = blockIdx.x;               // 512
    const int b = blk >> 4;
    const int hw0 = (blk & 15) << 6;
    const int tid = threadIdx.x;
    #pragma unroll
    for (int i = 0; i < 4; ++i) {
        int lin = i * 256 + tid;              // 0..1023
        int tl = lin >> 4, dg = lin & 15;
        int t = b * 1024 + hw0 + tl;
        int s0 = slot_of[t * 2], s1 = slot_of[t * 2 + 1];
        float p0 = top_prob[t * 2], p1 = top_prob[t * 2 + 1];
        short8v y0 = *(const short8v*)(pair_y + (size_t)s0 * 128 + dg * 8);
        short8v y1 = *(const short8v*)(pair_y + (size_t)s1 * 128 + dg * 8);
        #pragma unroll
        for (int j = 0; j < 8; ++j)
            ob[tl][dg * 8 + j] = p0 * bf2f((unsigned short)y0[j]) + p1 * bf2f((unsigned short)y1[j]);
    }
    __syncthreads();
    #pragma unroll
    for (int i = 0; i < 32; ++i) {
        int lin = i * 256 + tid;
        int d = lin >> 6, hwl = lin & 63;
        out[((size_t)b * 128 + d) * 1024 + hw0 + hwl] = ob[hwl][d];
    }
}

// ---------------- fallback per-token expert kernel ----------------------------
__global__ __launch_bounds__(256) void moe_expert_kernel(
    const float* __restrict__ x,
    const int* __restrict__ top_idx, const float* __restrict__ top_prob,
    const float* __restrict__ w1, const float* __restrict__ b1,
    const float* __restrict__ w2, const float* __restrict__ b2,
    float* __restrict__ out)
{
    __shared__ float xsB[128];
    __shared__ float hb[512];

    const int tid = threadIdx.x;
    const int t = blockIdx.x;
    const int b = t >> 10, hw = t & 1023;

    if (tid < 128)
        xsB[tid] = x[((size_t)b * 128 + tid) * NHW + hw];
    __syncthreads();

    float oacc = 0.f;
    #pragma unroll
    for (int k = 0; k < 2; ++k) {
        const int e = top_idx[t * 2 + k];
        const float pw = top_prob[t * 2 + k];
        const float* W1 = w1 + (size_t)e * (128 * 512);
        float a0 = 0.f, a1 = 0.f;
        for (int d = 0; d < 128; ++d) {
            float xv = xsB[d];
            a0 = fmaf(xv, W1[d * 512 + tid], a0);
            a1 = fmaf(xv, W1[d * 512 + tid + 256], a1);
        }
        hb[tid]       = fmaxf(a0 + b1[e * 512 + tid], 0.f);
        hb[tid + 256] = fmaxf(a1 + b1[e * 512 + tid + 256], 0.f);
        __syncthreads();
        if (tid < 128) {
            const float* W2 = w2 + (size_t)e * (512 * 128);
            float a = 0.f;
            for (int h = 0; h < 512; ++h)
                a = fmaf(hb[h], W2[h * 128 + tid], a);
            oacc = fmaf(pw, a + b2[e * 128 + tid], oacc);
        }
        __syncthreads();
    }
    if (tid < 128)
        out[((size_t)b * 128 + tid) * NHW + hw] = oacc;
}

// ---------------- host launch -------------------------------------------------
extern "C" void kernel_launch(void* const* d_in, const int* in_sizes, int n_in,
                              void* d_out, int out_size, void* d_ws, size_t ws_size,
                              hipStream_t stream) {
    const float* x       = (const float*)d_in[0];
    const float* gate_w  = (const float*)d_in[1];
    const float* gate_b  = (const float*)d_in[2];
    const float* noise_w = (const float*)d_in[3];
    const float* noise_b = (const float*)d_in[4];
    const float* w1      = (const float*)d_in[5];
    const float* b1      = (const float*)d_in[6];
    const float* w2      = (const float*)d_in[7];
    const float* b2      = (const float*)d_in[8];

    float* out   = (float*)d_out;                   // [32,128,32,32]
    float* gates = out + (size_t)NB * NC * NHW;     // [T,16]

    // workspace layout (byte offsets)
    const size_t OFF_POFF   = 0;          // 16 ints
    const size_t OFF_TOTAL  = 1024;       // 1 int
    const size_t OFF_B2E    = 4096;       // 544 ints
    const size_t OFF_B2C    = 8192;       // 544 ints
    const size_t OFF_TIDX   = 12288;      // T*2 ints
    const size_t OFF_RANK   = OFF_TIDX  + (size_t)NT * 2 * 4;
    const size_t OFF_SLOT   = OFF_RANK  + (size_t)NT * 2 * 4;
    const size_t OFF_PROB   = OFF_SLOT  + (size_t)NT * 2 * 4;
    const size_t OFF_BCNT   = OFF_PROB  + (size_t)NT * 2 * 4;     // 512*16 ints
    const size_t OFF_XTB    = OFF_BCNT  + (size_t)NGBLK * 16 * 4;
    const size_t OFF_W1BT   = OFF_XTB   + (size_t)NT * 128 * 2;
    const size_t OFF_W2BT   = OFF_W1BT  + (size_t)NE * 512 * 128 * 2;
    const size_t OFF_PTOK   = OFF_W2BT  + (size_t)NE * 128 * 512 * 2;
    const size_t NPAIR_PAD  = 67584;
    const size_t OFF_PAIRY  = OFF_PTOK  + NPAIR_PAD * 4;
    const size_t NEED       = OFF_PAIRY + NPAIR_PAD * 128 * 2;   // pair_y bf16

    char* ws = (char*)d_ws;
    int*   poff     = (int*)(ws + OFF_POFF);
    int*   total_ch = (int*)(ws + OFF_TOTAL);
    int*   blk2e    = (int*)(ws + OFF_B2E);
    int*   blk2c    = (int*)(ws + OFF_B2C);
    int*   top_idx  = (int*)(ws + OFF_TIDX);
    int*   rank     = (int*)(ws + OFF_RANK);
    int*   slot_of  = (int*)(ws + OFF_SLOT);
    float* top_prob = (float*)(ws + OFF_PROB);
    int*   bcnt     = (int*)(ws + OFF_BCNT);
    unsigned short* xtb    = (unsigned short*)(ws + OFF_XTB);
    unsigned short* w1bt   = (unsigned short*)(ws + OFF_W1BT);
    unsigned short* w2bt   = (unsigned short*)(ws + OFF_W2BT);
    int*   pair_tok = (int*)(ws + OFF_PTOK);
    unsigned short* pair_y = (unsigned short*)(ws + OFF_PAIRY);

    const int use_new = (ws_size >= NEED) ? 1 : 0;

    // gate (blocks 0..511) + weight transpose (blocks 512..1023) in one launch
    moe_gate_tw_kernel<<<use_new ? (NGBLK + 512) : NGBLK, 256, 0, stream>>>(
        x, gate_w, gate_b, noise_w, noise_b,
        gates, top_idx, top_prob, rank, bcnt, xtb,
        w1, w1bt, w2, w2bt, use_new);

    if (use_new) {
        scatter2_kernel<<<256, 256, 0, stream>>>(bcnt, top_idx, rank,
                                                 poff, blk2e, blk2c, total_ch,
                                                 pair_tok, slot_of);
        moe_mfma_kernel<<<528, 512, 0, stream>>>(
            xtb, pair_tok, blk2e, blk2c, poff, total_ch,
            w1bt, b1, w2bt, b2, pair_y);
        combine_kernel<<<512, 256, 0, stream>>>(pair_y, slot_of, top_prob, out);
    } else {
        moe_expert_kernel<<<NT, 256, 0, stream>>>(
            x, top_idx, top_prob, w1, b1, w2, b2, out);
    }
}